// Round 1
// baseline (16373.932 us; speedup 1.0000x reference)
//
#include <hip/hip_runtime.h>
#include <math.h>

#define BANDS 64
#define CHN   64
#define NN    16384
#define TOT   67108864   // 64*64*16384
#define KSPLIT 16
#define KCH   (NN / KSPLIT)   // 1024
#define ITE   20

// ---------------------------------------------------------------------------
// init: V = I per band, zero wsum + loss outputs
// ---------------------------------------------------------------------------
__global__ __launch_bounds__(256) void init_kernel(float* __restrict__ Vg,
                                                   float* __restrict__ losses,
                                                   float* __restrict__ wsum) {
    int id = blockIdx.x * 256 + threadIdx.x;   // 0..262143
    int i = (id >> 6) & 63, j = id & 63;
    Vg[id] = (i == j) ? 1.0f : 0.0f;
    if (id == 0) wsum[0] = 0.0f;
    if (id < 40) losses[id] = 0.0f;
}

// ---------------------------------------------------------------------------
// sum(W) for rho0 = 0.5*mean(W)
// ---------------------------------------------------------------------------
__global__ __launch_bounds__(256) void wsum_kernel(const float4* __restrict__ W4,
                                                   float* __restrict__ wsum) {
    size_t id = (size_t)blockIdx.x * 256 + threadIdx.x;
    size_t stride = (size_t)gridDim.x * 256;
    float acc = 0.0f;
    for (size_t i = id; i < (size_t)(TOT / 4); i += stride) {
        float4 v = W4[i];
        acc += (v.x + v.y) + (v.z + v.w);
    }
    #pragma unroll
    for (int o = 32; o; o >>= 1) acc += __shfl_down(acc, o, 64);
    __shared__ float red[4];
    int lane = threadIdx.x & 63, w = threadIdx.x >> 6;
    if (lane == 0) red[w] = acc;
    __syncthreads();
    if (threadIdx.x == 0) atomicAdd(wsum, red[0] + red[1] + red[2] + red[3]);
}

// ---------------------------------------------------------------------------
// syrk: Gpart[ks][b][64][64] = L[b][:, ks*KCH : (ks+1)*KCH] * (same)^T
// 64-thread wg, 8x8 register tile per thread, transposed LDS tile (stride 68
// keeps ds_read_b128 16B-aligned; 2-way bank aliasing only => conflict-free).
// ---------------------------------------------------------------------------
__global__ __launch_bounds__(64) void gemm_kernel(const float* __restrict__ L,
                                                  float* __restrict__ Gpart) {
    __shared__ float T[64 * 68];
    const int b = blockIdx.y, ks = blockIdx.x, t = threadIdx.x;
    const int tx = t & 7, ty = t >> 3;
    float acc[8][8];
    #pragma unroll
    for (int i = 0; i < 8; ++i)
        #pragma unroll
        for (int j = 0; j < 8; ++j) acc[i][j] = 0.0f;

    // lane t owns row t of the band; k-chunk [ks*KCH, ...)
    const float* Lb = L + (size_t)b * CHN * NN + (size_t)ks * KCH + (size_t)t * NN;

    float4 pf[16];
    #pragma unroll
    for (int j = 0; j < 16; ++j) pf[j] = ((const float4*)Lb)[j];

    for (int k0 = 0; k0 < KCH; k0 += 64) {
        // stage transposed: T[k][c] = L[c][k0+k]; writes are conflict-free
        #pragma unroll
        for (int j = 0; j < 16; ++j) {
            float4 v = pf[j];
            T[(4 * j + 0) * 68 + t] = v.x;
            T[(4 * j + 1) * 68 + t] = v.y;
            T[(4 * j + 2) * 68 + t] = v.z;
            T[(4 * j + 3) * 68 + t] = v.w;
        }
        __syncthreads();
        if (k0 + 64 < KCH) {
            const float4* nxt = (const float4*)(Lb + k0 + 64);
            #pragma unroll
            for (int j = 0; j < 16; ++j) pf[j] = nxt[j];
        }
        #pragma unroll 4
        for (int k = 0; k < 64; ++k) {
            const float* row = &T[k * 68];
            float4 A0 = *(const float4*)(row + 8 * ty);
            float4 A1 = *(const float4*)(row + 8 * ty + 4);
            float4 B0 = *(const float4*)(row + 8 * tx);
            float4 B1 = *(const float4*)(row + 8 * tx + 4);
            float av[8] = {A0.x, A0.y, A0.z, A0.w, A1.x, A1.y, A1.z, A1.w};
            float bv[8] = {B0.x, B0.y, B0.z, B0.w, B1.x, B1.y, B1.z, B1.w};
            #pragma unroll
            for (int i = 0; i < 8; ++i)
                #pragma unroll
                for (int j = 0; j < 8; ++j)
                    acc[i][j] = fmaf(av[i], bv[j], acc[i][j]);
        }
        __syncthreads();
    }
    float* Gp = Gpart + ((size_t)ks * BANDS + b) * 4096;
    #pragma unroll
    for (int i = 0; i < 8; ++i)
        #pragma unroll
        for (int j = 0; j < 8; ++j)
            Gp[(8 * ty + i) * 64 + 8 * tx + j] = acc[i][j];
}

// ---------------------------------------------------------------------------
// eig: per band, warm-started parallel Jacobi on B = V^T G V; V accumulates.
// Writes top-3 eigvecs (any order/sign -- projector invariant) to Ur[b][3][64].
// ---------------------------------------------------------------------------
__global__ __launch_bounds__(256) void eig_kernel(const float* __restrict__ Gpart,
                                                  float* __restrict__ Vg,
                                                  float* __restrict__ Ur,
                                                  int maxsweeps) {
    __shared__ float A[64 * 65];
    __shared__ float V[64 * 65];
    __shared__ float T[64 * 65];
    __shared__ float cs[32], sn[32];
    __shared__ int pa[32], pb[32];
    __shared__ int perm[64];
    __shared__ int topi[3];
    __shared__ float red[8];
    __shared__ int done;
    const int b = blockIdx.x, t = threadIdx.x;

    for (int m = t; m < 4096; m += 256) {
        int i = m >> 6, j = m & 63;
        float s = 0.0f;
        #pragma unroll
        for (int ks = 0; ks < KSPLIT; ++ks)
            s += Gpart[((size_t)ks * BANDS + b) * 4096 + m];
        A[i * 65 + j] = s;
        V[i * 65 + j] = Vg[(size_t)b * 4096 + m];
    }
    if (t < 64) perm[t] = t;
    if (t == 0) done = 0;
    __syncthreads();

    // T = A(=G) * V
    {
        int i = t >> 2, j0 = (t & 3) * 16;
        float accm[16];
        #pragma unroll
        for (int jj = 0; jj < 16; ++jj) accm[jj] = 0.0f;
        for (int k = 0; k < 64; ++k) {
            float a = A[i * 65 + k];
            #pragma unroll
            for (int jj = 0; jj < 16; ++jj) accm[jj] = fmaf(a, V[k * 65 + j0 + jj], accm[jj]);
        }
        __syncthreads();   // everyone finished reading A before we overwrite below
        #pragma unroll
        for (int jj = 0; jj < 16; ++jj) T[i * 65 + j0 + jj] = accm[jj];
    }
    __syncthreads();
    // A = V^T * T
    {
        int i = t >> 2, j0 = (t & 3) * 16;
        float accm[16];
        #pragma unroll
        for (int jj = 0; jj < 16; ++jj) accm[jj] = 0.0f;
        for (int k = 0; k < 64; ++k) {
            float v = V[k * 65 + i];
            #pragma unroll
            for (int jj = 0; jj < 16; ++jj) accm[jj] = fmaf(v, T[k * 65 + j0 + jj], accm[jj]);
        }
        __syncthreads();   // matmul reads of old A are done (it reads V,T only) -- but be safe
        #pragma unroll
        for (int jj = 0; jj < 16; ++jj) A[i * 65 + j0 + jj] = accm[jj];
    }
    __syncthreads();
    // symmetrize (kills fp asymmetry from the two matmuls)
    for (int m = t; m < 4096; m += 256) {
        int i = m >> 6, j = m & 63;
        if (i < j) {
            float av = 0.5f * (A[i * 65 + j] + A[j * 65 + i]);
            A[i * 65 + j] = av;
            A[j * 65 + i] = av;
        }
    }
    __syncthreads();

    for (int sweep = 0; sweep < maxsweeps; ++sweep) {
        for (int rnd = 0; rnd < 63; ++rnd) {
            int pv = 0, dst = 0;
            if (t < 64) {
                pv = perm[t];
                dst = (t == 0) ? 0 : ((t == 63) ? 1 : t + 1);
            }
            if (t < 32) {
                int p = perm[t], q = perm[63 - t];
                if (p > q) { int tmp = p; p = q; q = tmp; }
                float app = A[p * 65 + p], aqq = A[q * 65 + q], apq = A[p * 65 + q];
                float c = 1.0f, s = 0.0f;
                if (fabsf(apq) > 1e-9f * (fabsf(app) + fabsf(aqq)) + 1e-30f) {
                    float tau = (aqq - app) / (2.0f * apq);
                    float tt = 1.0f / (fabsf(tau) + sqrtf(1.0f + tau * tau));
                    if (tau < 0.0f) tt = -tt;
                    c = 1.0f / sqrtf(1.0f + tt * tt);
                    s = tt * c;
                }
                cs[t] = c; sn[t] = s; pa[t] = p; pb[t] = q;
            }
            __syncthreads();
            // row phase: A <- J^T A   (2048 tasks; contiguous j => conflict-free)
            for (int m = t; m < 2048; m += 256) {
                int j = m & 63, pr = m >> 6;
                int p = pa[pr], q = pb[pr];
                float c = cs[pr], s = sn[pr];
                float x = A[p * 65 + j], y = A[q * 65 + j];
                A[p * 65 + j] = c * x - s * y;
                A[q * 65 + j] = s * x + c * y;
            }
            __syncthreads();
            // col phase: A <- A J, V <- V J  (4096 tasks)
            for (int m = t; m < 4096; m += 256) {
                int i = m & 63, pr = (m >> 6) & 31;
                float* M = (m >> 11) ? V : A;
                int p = pa[pr], q = pb[pr];
                float c = cs[pr], s = sn[pr];
                float x = M[i * 65 + p], y = M[i * 65 + q];
                M[i * 65 + p] = c * x - s * y;
                M[i * 65 + q] = s * x + c * y;
            }
            if (t < 64) perm[dst] = pv;   // circle-method rotation
            __syncthreads();
        }
        // early exit when off-diagonal mass is at fp32 floor
        float offs = 0.0f, dgs = 0.0f;
        for (int m = t; m < 4096; m += 256) {
            int i = m >> 6, j = m & 63;
            float v = A[i * 65 + j];
            if (i == j) dgs += v * v; else offs += v * v;
        }
        #pragma unroll
        for (int o = 32; o; o >>= 1) {
            offs += __shfl_down(offs, o, 64);
            dgs += __shfl_down(dgs, o, 64);
        }
        if ((t & 63) == 0) { red[t >> 6] = offs; red[4 + (t >> 6)] = dgs; }
        __syncthreads();
        if (t == 0) {
            float off = red[0] + red[1] + red[2] + red[3];
            float dg = red[4] + red[5] + red[6] + red[7];
            if (off <= 1e-11f * dg) done = 1;
        }
        __syncthreads();
        if (done) break;
    }

    if (t == 0) {
        unsigned long long used = 0ull;
        for (int r = 0; r < 3; ++r) {
            float best = -3.4e38f; int bi = 0;
            for (int i = 0; i < 64; ++i) {
                float d = A[i * 65 + i];
                if (!((used >> i) & 1ull) && d > best) { best = d; bi = i; }
            }
            used |= (1ull << bi);
            topi[r] = bi;
        }
    }
    __syncthreads();
    if (t < 192) {
        int r = t >> 6, c = t & 63;
        Ur[((size_t)b * 3 + r) * 64 + c] = V[c * 65 + topi[r]];
    }
    for (int m = t; m < 4096; m += 256)
        Vg[(size_t)b * 4096 + m] = V[(m >> 6) * 65 + (m & 63)];
}

// ---------------------------------------------------------------------------
// fuse: t = Ur^T L ; UV = Ur t ; losses ; L_new = x + mu*(UV-x), in place.
// Last iteration writes UV (the output) instead of L_new.
// ---------------------------------------------------------------------------
__global__ __launch_bounds__(256) void fuse_kernel(const float* __restrict__ Lsrc,
                                                   const float* __restrict__ X,
                                                   const float* __restrict__ W,
                                                   float* __restrict__ Ldst,
                                                   const float* __restrict__ Ur,
                                                   const float* __restrict__ wsum,
                                                   float alphapow,
                                                   float* __restrict__ outLF,
                                                   float* __restrict__ outL,
                                                   int last) {
    __shared__ float U0[64], U1[64], U2[64];
    __shared__ float red[8];
    const int b = blockIdx.y, nb = blockIdx.x, t = threadIdx.x;
    if (t < 64) {
        U0[t] = Ur[((size_t)b * 3 + 0) * 64 + t];
        U1[t] = Ur[((size_t)b * 3 + 1) * 64 + t];
        U2[t] = Ur[((size_t)b * 3 + 2) * 64 + t];
    }
    __syncthreads();
    size_t base = (size_t)b * CHN * NN;
    size_t n = ((size_t)nb * 256 + t) * 4;
    const float4* Lp = (const float4*)(Lsrc + base + n);

    float4 t0 = {0, 0, 0, 0}, t1 = {0, 0, 0, 0}, t2 = {0, 0, 0, 0};
    #pragma unroll 4
    for (int c = 0; c < 64; ++c) {
        float4 v = Lp[c * (NN / 4)];
        float u0 = U0[c], u1 = U1[c], u2 = U2[c];
        t0.x = fmaf(u0, v.x, t0.x); t0.y = fmaf(u0, v.y, t0.y);
        t0.z = fmaf(u0, v.z, t0.z); t0.w = fmaf(u0, v.w, t0.w);
        t1.x = fmaf(u1, v.x, t1.x); t1.y = fmaf(u1, v.y, t1.y);
        t1.z = fmaf(u1, v.z, t1.z); t1.w = fmaf(u1, v.w, t1.w);
        t2.x = fmaf(u2, v.x, t2.x); t2.y = fmaf(u2, v.y, t2.y);
        t2.z = fmaf(u2, v.z, t2.z); t2.w = fmaf(u2, v.w, t2.w);
    }
    float rho = 0.5f * wsum[0] * (1.0f / 67108864.0f) * alphapow;
    const float4* xp = (const float4*)(X + base + n);
    const float4* wp = (const float4*)(W + base + n);
    float4* op = (float4*)(Ldst + base + n);
    float accL = 0.0f, accF = 0.0f;
    #pragma unroll 2
    for (int c = 0; c < 64; ++c) {
        float u0 = U0[c], u1 = U1[c], u2 = U2[c];
        float4 uv;
        uv.x = u0 * t0.x + u1 * t1.x + u2 * t2.x;
        uv.y = u0 * t0.y + u1 * t1.y + u2 * t2.y;
        uv.z = u0 * t0.z + u1 * t1.z + u2 * t2.z;
        uv.w = u0 * t0.w + u1 * t1.w + u2 * t2.w;
        float4 xx = xp[c * (NN / 4)];
        float4 ww = wp[c * (NN / 4)];
        float dx = uv.x - xx.x, dy = uv.y - xx.y, dz = uv.z - xx.z, dw = uv.w - xx.w;
        accL += uv.x * uv.x + uv.y * uv.y + uv.z * uv.z + uv.w * uv.w;
        accF += ww.x * dx * dx + ww.y * dy * dy + ww.z * dz * dz + ww.w * dw * dw;
        float4 res;
        if (last) {
            res = uv;
        } else {
            res.x = xx.x + (rho / (ww.x + rho)) * dx;
            res.y = xx.y + (rho / (ww.y + rho)) * dy;
            res.z = xx.z + (rho / (ww.z + rho)) * dz;
            res.w = xx.w + (rho / (ww.w + rho)) * dw;
        }
        op[c * (NN / 4)] = res;
    }
    #pragma unroll
    for (int o = 32; o; o >>= 1) {
        accL += __shfl_down(accL, o, 64);
        accF += __shfl_down(accF, o, 64);
    }
    int lane = t & 63, w = t >> 6;
    if (lane == 0) { red[w] = accF; red[4 + w] = accL; }
    __syncthreads();
    if (t == 0) {
        atomicAdd(outLF, (red[0] + red[1] + red[2] + red[3]) * (1.0f / 67108864.0f));
        atomicAdd(outL, (red[4] + red[5] + red[6] + red[7]) * (1.0f / 67108864.0f));
    }
}

// ---------------------------------------------------------------------------
extern "C" void kernel_launch(void* const* d_in, const int* in_sizes, int n_in,
                              void* d_out, int out_size, void* d_ws, size_t ws_size,
                              hipStream_t stream) {
    (void)in_sizes; (void)n_in; (void)out_size; (void)ws_size;
    const float* X = (const float*)d_in[0];
    const float* W = (const float*)d_in[1];
    float* out = (float*)d_out;

    float* wsf = (float*)d_ws;
    float* wsum = wsf;                       // 1 (padded to 64)
    float* Vg = wsf + 64;                    // 64*64*64 = 262144
    float* UrB = Vg + 262144;                // 64*3*64  = 12288
    float* Gpart = UrB + 12288;              // 16*64*4096 = 4194304  (~18 MB total)
    float* losses = out + TOT;               // [0..19]=loss_F, [20..39]=loss

    hipLaunchKernelGGL(init_kernel, dim3(1024), dim3(256), 0, stream, Vg, losses, wsum);
    hipLaunchKernelGGL(wsum_kernel, dim3(2048), dim3(256), 0, stream, (const float4*)W, wsum);

    for (int i = 0; i < ITE; ++i) {
        const float* Ls = (i == 0) ? X : out;   // L lives in the UV output region
        hipLaunchKernelGGL(gemm_kernel, dim3(KSPLIT, BANDS), dim3(64), 0, stream, Ls, Gpart);
        hipLaunchKernelGGL(eig_kernel, dim3(BANDS), dim3(256), 0, stream, Gpart, Vg, UrB,
                           (i == 0) ? 14 : 6);
        float ap = (float)pow(1.05, (double)i);
        hipLaunchKernelGGL(fuse_kernel, dim3(16, BANDS), dim3(256), 0, stream,
                           Ls, X, W, out, UrB, wsum, ap,
                           losses + i, losses + 20 + i, (i == ITE - 1) ? 1 : 0);
    }
}

// Round 2
// 12177.827 us; speedup vs baseline: 1.3446x; 1.3446x over previous
//
#include <hip/hip_runtime.h>
#include <math.h>

#define BANDS 64
#define CHN   64
#define NN    16384
#define TOT   67108864   // 64*64*16384
#define KSPLIT 16
#define KCH   (NN / KSPLIT)   // 1024
#define ITE   20

// ---------------------------------------------------------------------------
// init: V = I per band, zero wsum + loss outputs
// ---------------------------------------------------------------------------
__global__ __launch_bounds__(256) void init_kernel(float* __restrict__ Vg,
                                                   float* __restrict__ losses,
                                                   float* __restrict__ wsum) {
    int id = blockIdx.x * 256 + threadIdx.x;   // 0..262143
    int i = (id >> 6) & 63, j = id & 63;
    Vg[id] = (i == j) ? 1.0f : 0.0f;
    if (id == 0) wsum[0] = 0.0f;
    if (id < 40) losses[id] = 0.0f;
}

// ---------------------------------------------------------------------------
// sum(W) for rho0 = 0.5*mean(W)
// ---------------------------------------------------------------------------
__global__ __launch_bounds__(256) void wsum_kernel(const float4* __restrict__ W4,
                                                   float* __restrict__ wsum) {
    size_t id = (size_t)blockIdx.x * 256 + threadIdx.x;
    size_t stride = (size_t)gridDim.x * 256;
    float acc = 0.0f;
    for (size_t i = id; i < (size_t)(TOT / 4); i += stride) {
        float4 v = W4[i];
        acc += (v.x + v.y) + (v.z + v.w);
    }
    #pragma unroll
    for (int o = 32; o; o >>= 1) acc += __shfl_down(acc, o, 64);
    __shared__ float red[4];
    int lane = threadIdx.x & 63, w = threadIdx.x >> 6;
    if (lane == 0) red[w] = acc;
    __syncthreads();
    if (threadIdx.x == 0) atomicAdd(wsum, red[0] + red[1] + red[2] + red[3]);
}

// ---------------------------------------------------------------------------
// syrk: Gpart[ks][b][64][64] = L[b][:, ks*KCH : (ks+1)*KCH] * (same)^T
// 64-thread wg, 8x8 register tile per thread, transposed LDS tile (stride 68
// keeps ds_read_b128 16B-aligned; 2-way bank aliasing only => conflict-free).
// ---------------------------------------------------------------------------
__global__ __launch_bounds__(64) void gemm_kernel(const float* __restrict__ L,
                                                  float* __restrict__ Gpart) {
    __shared__ float T[64 * 68];
    const int b = blockIdx.y, ks = blockIdx.x, t = threadIdx.x;
    const int tx = t & 7, ty = t >> 3;
    float acc[8][8];
    #pragma unroll
    for (int i = 0; i < 8; ++i)
        #pragma unroll
        for (int j = 0; j < 8; ++j) acc[i][j] = 0.0f;

    // lane t owns row t of the band; k-chunk [ks*KCH, ...)
    const float* Lb = L + (size_t)b * CHN * NN + (size_t)ks * KCH + (size_t)t * NN;

    float4 pf[16];
    #pragma unroll
    for (int j = 0; j < 16; ++j) pf[j] = ((const float4*)Lb)[j];

    for (int k0 = 0; k0 < KCH; k0 += 64) {
        // stage transposed: T[k][c] = L[c][k0+k]; writes are conflict-free
        #pragma unroll
        for (int j = 0; j < 16; ++j) {
            float4 v = pf[j];
            T[(4 * j + 0) * 68 + t] = v.x;
            T[(4 * j + 1) * 68 + t] = v.y;
            T[(4 * j + 2) * 68 + t] = v.z;
            T[(4 * j + 3) * 68 + t] = v.w;
        }
        __syncthreads();
        if (k0 + 64 < KCH) {
            const float4* nxt = (const float4*)(Lb + k0 + 64);
            #pragma unroll
            for (int j = 0; j < 16; ++j) pf[j] = nxt[j];
        }
        #pragma unroll 4
        for (int k = 0; k < 64; ++k) {
            const float* row = &T[k * 68];
            float4 A0 = *(const float4*)(row + 8 * ty);
            float4 A1 = *(const float4*)(row + 8 * ty + 4);
            float4 B0 = *(const float4*)(row + 8 * tx);
            float4 B1 = *(const float4*)(row + 8 * tx + 4);
            float av[8] = {A0.x, A0.y, A0.z, A0.w, A1.x, A1.y, A1.z, A1.w};
            float bv[8] = {B0.x, B0.y, B0.z, B0.w, B1.x, B1.y, B1.z, B1.w};
            #pragma unroll
            for (int i = 0; i < 8; ++i)
                #pragma unroll
                for (int j = 0; j < 8; ++j)
                    acc[i][j] = fmaf(av[i], bv[j], acc[i][j]);
        }
        __syncthreads();
    }
    float* Gp = Gpart + ((size_t)ks * BANDS + b) * 4096;
    #pragma unroll
    for (int i = 0; i < 8; ++i)
        #pragma unroll
        for (int j = 0; j < 8; ++j)
            Gp[(8 * ty + i) * 64 + 8 * tx + j] = acc[i][j];
}

// ---------------------------------------------------------------------------
// eig: per band, warm-started parallel Jacobi on B = V^T G V; V accumulates.
// Rotation pairs within a round are DISJOINT, so all LDS reads of a phase are
// batched into register arrays first (one waitcnt), then computed, then
// written — removes the read-write-read serialization that cost 3.3us/round.
// A and V live in one shared array so the col phase indexes uniformly.
// ---------------------------------------------------------------------------
__global__ __launch_bounds__(256) void eig_kernel(const float* __restrict__ Gpart,
                                                  float* __restrict__ Vg,
                                                  float* __restrict__ Ur,
                                                  int maxsweeps) {
    __shared__ float SH[64 * 65 * 3];   // A | V | T, each 64x65 (stride 65)
    float* A = SH;
    float* V = SH + 4160;
    float* T = SH + 8320;
    __shared__ float cs[32], sn[32];
    __shared__ int pa[32], pb[32];
    __shared__ int perm[64];
    __shared__ int topi[3];
    __shared__ float red[8];
    __shared__ int done;
    const int b = blockIdx.x, t = threadIdx.x;

    for (int m = t; m < 4096; m += 256) {
        int i = m >> 6, j = m & 63;
        float s = 0.0f;
        #pragma unroll
        for (int ks = 0; ks < KSPLIT; ++ks)
            s += Gpart[((size_t)ks * BANDS + b) * 4096 + m];
        A[i * 65 + j] = s;
        V[i * 65 + j] = Vg[(size_t)b * 4096 + m];
    }
    if (t < 64) perm[t] = t;
    if (t == 0) done = 0;
    __syncthreads();

    // T = A(=G) * V   (T disjoint from A,V -> no barrier before writes)
    {
        int i = t >> 2, j0 = (t & 3) * 16;
        float accm[16];
        #pragma unroll
        for (int jj = 0; jj < 16; ++jj) accm[jj] = 0.0f;
        for (int k = 0; k < 64; ++k) {
            float a = A[i * 65 + k];
            #pragma unroll
            for (int jj = 0; jj < 16; ++jj) accm[jj] = fmaf(a, V[k * 65 + j0 + jj], accm[jj]);
        }
        #pragma unroll
        for (int jj = 0; jj < 16; ++jj) T[i * 65 + j0 + jj] = accm[jj];
    }
    __syncthreads();
    // A = V^T * T   (mm reads V,T only -> safe to overwrite A in place)
    {
        int i = t >> 2, j0 = (t & 3) * 16;
        float accm[16];
        #pragma unroll
        for (int jj = 0; jj < 16; ++jj) accm[jj] = 0.0f;
        for (int k = 0; k < 64; ++k) {
            float v = V[k * 65 + i];
            #pragma unroll
            for (int jj = 0; jj < 16; ++jj) accm[jj] = fmaf(v, T[k * 65 + j0 + jj], accm[jj]);
        }
        #pragma unroll
        for (int jj = 0; jj < 16; ++jj) A[i * 65 + j0 + jj] = accm[jj];
    }
    __syncthreads();
    // symmetrize (kills fp asymmetry from the two matmuls)
    for (int m = t; m < 4096; m += 256) {
        int i = m >> 6, j = m & 63;
        if (i < j) {
            float av = 0.5f * (A[i * 65 + j] + A[j * 65 + i]);
            A[i * 65 + j] = av;
            A[j * 65 + i] = av;
        }
    }
    __syncthreads();

    for (int sweep = 0; sweep < maxsweeps; ++sweep) {
        for (int rnd = 0; rnd < 63; ++rnd) {
            int pv = 0, dst = 0;
            if (t < 64) {
                pv = perm[t];
                dst = (t == 0) ? 0 : ((t == 63) ? 1 : t + 1);
            }
            if (t < 32) {
                int p = perm[t], q = perm[63 - t];
                if (p > q) { int tmp = p; p = q; q = tmp; }
                float app = A[p * 65 + p], aqq = A[q * 65 + q], apq = A[p * 65 + q];
                float c = 1.0f, s = 0.0f;
                if (fabsf(apq) > 1e-9f * (fabsf(app) + fabsf(aqq)) + 1e-30f) {
                    float tau = (aqq - app) / (2.0f * apq);
                    float tt = 1.0f / (fabsf(tau) + sqrtf(1.0f + tau * tau));
                    if (tau < 0.0f) tt = -tt;
                    c = 1.0f / sqrtf(1.0f + tt * tt);
                    s = tt * c;
                }
                cs[t] = c; sn[t] = s; pa[t] = p; pb[t] = q;
            }
            __syncthreads();
            // row phase: A <- J^T A. 8 tasks/thread, reads batched (pairs disjoint).
            {
                int ip[8], iq[8];
                float cc[8], ssv[8], xv[8], yv[8];
                #pragma unroll
                for (int u = 0; u < 8; ++u) {
                    int m = t + (u << 8);
                    int j = m & 63, pr = m >> 6;
                    ip[u] = pa[pr] * 65 + j;
                    iq[u] = pb[pr] * 65 + j;
                    cc[u] = cs[pr]; ssv[u] = sn[pr];
                }
                #pragma unroll
                for (int u = 0; u < 8; ++u) { xv[u] = A[ip[u]]; yv[u] = A[iq[u]]; }
                #pragma unroll
                for (int u = 0; u < 8; ++u) {
                    A[ip[u]] = cc[u] * xv[u] - ssv[u] * yv[u];
                    A[iq[u]] = ssv[u] * xv[u] + cc[u] * yv[u];
                }
            }
            __syncthreads();
            // col phase: A <- A J and V <- V J. 16 tasks/thread, reads batched.
            {
                int ip[16], iq[16];
                float cc[16], ssv[16], xv[16], yv[16];
                #pragma unroll
                for (int u = 0; u < 16; ++u) {
                    int m = t + (u << 8);
                    int i = m & 63, pr = (m >> 6) & 31;
                    int base = (m >> 11) * 4160;   // 0 -> A, 1 -> V
                    ip[u] = base + i * 65 + pa[pr];
                    iq[u] = base + i * 65 + pb[pr];
                    cc[u] = cs[pr]; ssv[u] = sn[pr];
                }
                #pragma unroll
                for (int u = 0; u < 16; ++u) { xv[u] = SH[ip[u]]; yv[u] = SH[iq[u]]; }
                #pragma unroll
                for (int u = 0; u < 16; ++u) {
                    SH[ip[u]] = cc[u] * xv[u] - ssv[u] * yv[u];
                    SH[iq[u]] = ssv[u] * xv[u] + cc[u] * yv[u];
                }
            }
            if (t < 64) perm[dst] = pv;   // circle-method rotation
            __syncthreads();
        }
        // early exit when off-diagonal mass is at fp32 floor
        float offs = 0.0f, dgs = 0.0f;
        for (int m = t; m < 4096; m += 256) {
            int i = m >> 6, j = m & 63;
            float v = A[i * 65 + j];
            if (i == j) dgs += v * v; else offs += v * v;
        }
        #pragma unroll
        for (int o = 32; o; o >>= 1) {
            offs += __shfl_down(offs, o, 64);
            dgs += __shfl_down(dgs, o, 64);
        }
        if ((t & 63) == 0) { red[t >> 6] = offs; red[4 + (t >> 6)] = dgs; }
        __syncthreads();
        if (t == 0) {
            float off = red[0] + red[1] + red[2] + red[3];
            float dg = red[4] + red[5] + red[6] + red[7];
            if (off <= 1e-11f * dg) done = 1;
        }
        __syncthreads();
        if (done) break;
    }

    if (t == 0) {
        unsigned long long used = 0ull;
        for (int r = 0; r < 3; ++r) {
            float best = -3.4e38f; int bi = 0;
            for (int i = 0; i < 64; ++i) {
                float d = A[i * 65 + i];
                if (!((used >> i) & 1ull) && d > best) { best = d; bi = i; }
            }
            used |= (1ull << bi);
            topi[r] = bi;
        }
    }
    __syncthreads();
    if (t < 192) {
        int r = t >> 6, c = t & 63;
        Ur[((size_t)b * 3 + r) * 64 + c] = V[c * 65 + topi[r]];
    }
    for (int m = t; m < 4096; m += 256)
        Vg[(size_t)b * 4096 + m] = V[(m >> 6) * 65 + (m & 63)];
}

// ---------------------------------------------------------------------------
// fuse: t = Ur^T L ; UV = Ur t ; losses ; L_new = x + mu*(UV-x), in place.
// Last iteration writes UV (the output) instead of L_new.
// ---------------------------------------------------------------------------
__global__ __launch_bounds__(256) void fuse_kernel(const float* __restrict__ Lsrc,
                                                   const float* __restrict__ X,
                                                   const float* __restrict__ W,
                                                   float* __restrict__ Ldst,
                                                   const float* __restrict__ Ur,
                                                   const float* __restrict__ wsum,
                                                   float alphapow,
                                                   float* __restrict__ outLF,
                                                   float* __restrict__ outL,
                                                   int last) {
    __shared__ float U0[64], U1[64], U2[64];
    __shared__ float red[8];
    const int b = blockIdx.y, nb = blockIdx.x, t = threadIdx.x;
    if (t < 64) {
        U0[t] = Ur[((size_t)b * 3 + 0) * 64 + t];
        U1[t] = Ur[((size_t)b * 3 + 1) * 64 + t];
        U2[t] = Ur[((size_t)b * 3 + 2) * 64 + t];
    }
    __syncthreads();
    size_t base = (size_t)b * CHN * NN;
    size_t n = ((size_t)nb * 256 + t) * 4;
    const float4* Lp = (const float4*)(Lsrc + base + n);

    float4 t0 = {0, 0, 0, 0}, t1 = {0, 0, 0, 0}, t2 = {0, 0, 0, 0};
    #pragma unroll 4
    for (int c = 0; c < 64; ++c) {
        float4 v = Lp[c * (NN / 4)];
        float u0 = U0[c], u1 = U1[c], u2 = U2[c];
        t0.x = fmaf(u0, v.x, t0.x); t0.y = fmaf(u0, v.y, t0.y);
        t0.z = fmaf(u0, v.z, t0.z); t0.w = fmaf(u0, v.w, t0.w);
        t1.x = fmaf(u1, v.x, t1.x); t1.y = fmaf(u1, v.y, t1.y);
        t1.z = fmaf(u1, v.z, t1.z); t1.w = fmaf(u1, v.w, t1.w);
        t2.x = fmaf(u2, v.x, t2.x); t2.y = fmaf(u2, v.y, t2.y);
        t2.z = fmaf(u2, v.z, t2.z); t2.w = fmaf(u2, v.w, t2.w);
    }
    float rho = 0.5f * wsum[0] * (1.0f / 67108864.0f) * alphapow;
    const float4* xp = (const float4*)(X + base + n);
    const float4* wp = (const float4*)(W + base + n);
    float4* op = (float4*)(Ldst + base + n);
    float accL = 0.0f, accF = 0.0f;
    #pragma unroll 2
    for (int c = 0; c < 64; ++c) {
        float u0 = U0[c], u1 = U1[c], u2 = U2[c];
        float4 uv;
        uv.x = u0 * t0.x + u1 * t1.x + u2 * t2.x;
        uv.y = u0 * t0.y + u1 * t1.y + u2 * t2.y;
        uv.z = u0 * t0.z + u1 * t1.z + u2 * t2.z;
        uv.w = u0 * t0.w + u1 * t1.w + u2 * t2.w;
        float4 xx = xp[c * (NN / 4)];
        float4 ww = wp[c * (NN / 4)];
        float dx = uv.x - xx.x, dy = uv.y - xx.y, dz = uv.z - xx.z, dw = uv.w - xx.w;
        accL += uv.x * uv.x + uv.y * uv.y + uv.z * uv.z + uv.w * uv.w;
        accF += ww.x * dx * dx + ww.y * dy * dy + ww.z * dz * dz + ww.w * dw * dw;
        float4 res;
        if (last) {
            res = uv;
        } else {
            res.x = xx.x + (rho / (ww.x + rho)) * dx;
            res.y = xx.y + (rho / (ww.y + rho)) * dy;
            res.z = xx.z + (rho / (ww.z + rho)) * dz;
            res.w = xx.w + (rho / (ww.w + rho)) * dw;
        }
        op[c * (NN / 4)] = res;
    }
    #pragma unroll
    for (int o = 32; o; o >>= 1) {
        accL += __shfl_down(accL, o, 64);
        accF += __shfl_down(accF, o, 64);
    }
    int lane = t & 63, w = t >> 6;
    if (lane == 0) { red[w] = accF; red[4 + w] = accL; }
    __syncthreads();
    if (t == 0) {
        atomicAdd(outLF, (red[0] + red[1] + red[2] + red[3]) * (1.0f / 67108864.0f));
        atomicAdd(outL, (red[4] + red[5] + red[6] + red[7]) * (1.0f / 67108864.0f));
    }
}

// ---------------------------------------------------------------------------
extern "C" void kernel_launch(void* const* d_in, const int* in_sizes, int n_in,
                              void* d_out, int out_size, void* d_ws, size_t ws_size,
                              hipStream_t stream) {
    (void)in_sizes; (void)n_in; (void)out_size; (void)ws_size;
    const float* X = (const float*)d_in[0];
    const float* W = (const float*)d_in[1];
    float* out = (float*)d_out;

    float* wsf = (float*)d_ws;
    float* wsum = wsf;                       // 1 (padded to 64)
    float* Vg = wsf + 64;                    // 64*64*64 = 262144
    float* UrB = Vg + 262144;                // 64*3*64  = 12288
    float* Gpart = UrB + 12288;              // 16*64*4096 = 4194304  (~18 MB total)
    float* losses = out + TOT;               // [0..19]=loss_F, [20..39]=loss

    hipLaunchKernelGGL(init_kernel, dim3(1024), dim3(256), 0, stream, Vg, losses, wsum);
    hipLaunchKernelGGL(wsum_kernel, dim3(2048), dim3(256), 0, stream, (const float4*)W, wsum);

    for (int i = 0; i < ITE; ++i) {
        const float* Ls = (i == 0) ? X : out;   // L lives in the UV output region
        hipLaunchKernelGGL(gemm_kernel, dim3(KSPLIT, BANDS), dim3(64), 0, stream, Ls, Gpart);
        hipLaunchKernelGGL(eig_kernel, dim3(BANDS), dim3(256), 0, stream, Gpart, Vg, UrB,
                           (i == 0) ? 14 : 6);
        float ap = (float)pow(1.05, (double)i);
        hipLaunchKernelGGL(fuse_kernel, dim3(16, BANDS), dim3(256), 0, stream,
                           Ls, X, W, out, UrB, wsum, ap,
                           losses + i, losses + 20 + i, (i == ITE - 1) ? 1 : 0);
    }
}